// Round 10
// baseline (384.085 us; speedup 1.0000x reference)
//
#include <hip/hip_runtime.h>
#include <hip/hip_bf16.h>

#define NPTS 30000
#define CH 96
#define KOFF 81
#define NB 8
#define HID 24
#define EPSV 1e-5f
#define RT 3                 // 16-row groups per wave (48 rows)
#define GSPLIT 625           // 30000 / 48
#define KSPLIT 4             // k slices: 20,20,20,21
#define PSTRIDE (96 * NPTS)  // elements per partial slice

typedef __attribute__((ext_vector_type(8))) short bf16x8;
typedef __attribute__((ext_vector_type(4))) float f32x4;

__device__ __forceinline__ ushort f2bf(float f) {
    union { float f; unsigned int u; } x; x.f = f;
    unsigned int u = x.u;
    unsigned int r = (u + 0x7fffu + ((u >> 16) & 1u)) >> 16;
    return (ushort)r;
}
__device__ __forceinline__ float bf2f(ushort u) {
    union { float f; unsigned int i; } x; x.i = ((unsigned int)u) << 16; return x.f;
}

// compute BN scale/shift into LDS (all blocks redundantly; cheap)
__device__ __forceinline__ void bn_coeffs(const float* __restrict__ ssum,
                                          const float* __restrict__ ssq,
                                          const float* __restrict__ g,
                                          const float* __restrict__ b,
                                          float* s_scale, float* s_shift) {
    int t = threadIdx.x;
    if (t < 96) {
        float mean = ssum[t] * (1.0f / NPTS);
        float var = ssq[t] * (1.0f / NPTS) - mean * mean;
        float sc = g[t] * rsqrtf(var + EPSV);
        s_scale[t] = sc;
        s_shift[t] = b[t] - mean * sc;
    }
    __syncthreads();
}

__device__ __forceinline__ int lowb(const int* __restrict__ bids, int v) {
    int lo = 0, hi = NPTS;
    while (lo < hi) { int m = (lo + hi) >> 1; if (bids[m] < v) lo = m + 1; else hi = m; }
    return lo;
}

// ---------------- fused prep kernel ----------------
// [0,2813): feats f32 -> bf16
// [2813,3282): nbr[n][k] -> nbrT[k][n]
// [3282,3444): W[k][c][d] -> chunk-major wt[k][q][d][j]
// 3444: batch boundaries
__global__ __launch_bounds__(256) void k_prep(const float* __restrict__ feats,
                                              const float* __restrict__ W1,
                                              const float* __restrict__ W2,
                                              const int* __restrict__ nbr,
                                              const int* __restrict__ bids,
                                              ushort* __restrict__ featsbf,
                                              int* __restrict__ nbrT,
                                              ushort* __restrict__ wt1,
                                              ushort* __restrict__ wt2,
                                              int* __restrict__ boundsI) {
    __shared__ __align__(16) char smem[36864];
    int bid = blockIdx.x, tid = threadIdx.x;
    if (bid < 2813) {
        int t = bid * 256 + tid;
        if (t < 720000) {
            float4 v = reinterpret_cast<const float4*>(feats)[t];
            ushort4 o;
            o.x = f2bf(v.x); o.y = f2bf(v.y); o.z = f2bf(v.z); o.w = f2bf(v.w);
            reinterpret_cast<ushort4*>(featsbf)[t] = o;
        }
    } else if (bid < 3282) {
        int* lds = (int*)smem;
        int n0 = (bid - 2813) * 64;
        int rows = min(64, NPTS - n0);
        int cnt = rows * 81;
        for (int i = tid; i < cnt; i += 256) lds[i] = nbr[n0 * 81 + i];
        __syncthreads();
        for (int o = tid; o < cnt; o += 256) {
            int kk = o / rows, r = o - kk * rows;
            nbrT[kk * NPTS + n0 + r] = lds[r * 81 + kk];
        }
    } else if (bid < 3444) {
        float* lds = (float*)smem;
        int b = bid - 3282;
        int k = (b < 81) ? b : b - 81;
        const float* src = ((b < 81) ? W1 : W2) + k * 9216;
        ushort* dst = ((b < 81) ? wt1 : wt2) + k * 9216;
        for (int j = tid; j < 9216; j += 256) lds[j] = src[j];  // lds[c*96+d]
        __syncthreads();
        for (int o = tid; o < 9216; o += 256) {
            int q = o / 768, rem = o - q * 768, d = rem >> 3, j = rem & 7;
            dst[o] = f2bf(lds[(q * 8 + j) * 96 + d]);
        }
    } else {
        if (tid < 9) boundsI[tid] = lowb(bids, tid);
    }
}

// ---------------- conv: wave-per-block, pipelined, plain bf16 partial stores ----
// xbf: [NPTS][96] bf16; wt: [81][12][96][8]; nbrT: [81][NPTS]
// P: [KSPLIT][96][NPTS] bf16 col-major partials
__global__ __launch_bounds__(64) void k_conv(const ushort* __restrict__ xbf,
                                             const ushort* __restrict__ wt,
                                             const int* __restrict__ nbrT,
                                             ushort* __restrict__ P) {
    const int lane = threadIdx.x;
    const int slice = blockIdx.x / GSPLIT;
    const int g = blockIdx.x % GSPLIT;
    const int k0 = slice * 20;
    const int k1 = k0 + ((slice == 3) ? 21 : 20);
    const int r16 = lane & 15, kg = lane >> 4;
    const int row0 = g * 48;

    f32x4 zero4 = {0.f, 0.f, 0.f, 0.f};
    f32x4 acc[RT][6];
#pragma unroll
    for (int rt = 0; rt < RT; ++rt)
#pragma unroll
        for (int db = 0; db < 6; ++db) acc[rt][db] = zero4;

    int ia[RT], ib[RT];
    bf16x8 aP[RT][3], aQ[RT][3];

    // prologue: A(k0) into aP, idx(k0+1) into ib
#pragma unroll
    for (int rt = 0; rt < RT; ++rt) ia[rt] = nbrT[k0 * NPTS + row0 + rt * 16 + r16];
#pragma unroll
    for (int rt = 0; rt < RT; ++rt) {
        const ushort* as = xbf + ia[rt] * 96 + kg * 8;
#pragma unroll
        for (int c = 0; c < 3; ++c) aP[rt][c] = *reinterpret_cast<const bf16x8*>(as + c * 32);
    }
    {
        int kn = (k0 + 1 < k1) ? (k0 + 1) : k0;
#pragma unroll
        for (int rt = 0; rt < RT; ++rt) ib[rt] = nbrT[kn * NPTS + row0 + rt * 16 + r16];
    }

    int k = k0;
    while (true) {
        // ---- consume aP(k), prefetch aQ(k+1) via ib, load ia=idx(k+2) ----
        {
            const ushort* wk = wt + k * 9216;
            bf16x8 bfrag[3][6];
#pragma unroll
            for (int c = 0; c < 3; ++c) {
                const int q = c * 4 + kg;
#pragma unroll
                for (int db = 0; db < 6; ++db)
                    bfrag[c][db] = *reinterpret_cast<const bf16x8*>(
                        wk + q * 768 + (db * 16 + r16) * 8);
            }
            if (k + 1 < k1) {
#pragma unroll
                for (int rt = 0; rt < RT; ++rt) {
                    const ushort* as = xbf + ib[rt] * 96 + kg * 8;
#pragma unroll
                    for (int c = 0; c < 3; ++c)
                        aQ[rt][c] = *reinterpret_cast<const bf16x8*>(as + c * 32);
                }
            }
            if (k + 2 < k1) {
#pragma unroll
                for (int rt = 0; rt < RT; ++rt)
                    ia[rt] = nbrT[(k + 2) * NPTS + row0 + rt * 16 + r16];
            }
#pragma unroll
            for (int c = 0; c < 3; ++c)
#pragma unroll
                for (int rt = 0; rt < RT; ++rt)
#pragma unroll
                    for (int db = 0; db < 6; ++db)
                        acc[rt][db] = __builtin_amdgcn_mfma_f32_16x16x32_bf16(
                            aP[rt][c], bfrag[c][db], acc[rt][db], 0, 0, 0);
        }
        ++k; if (k >= k1) break;
        // ---- consume aQ(k), prefetch aP(k+1) via ia, load ib=idx(k+2) ----
        {
            const ushort* wk = wt + k * 9216;
            bf16x8 bfrag[3][6];
#pragma unroll
            for (int c = 0; c < 3; ++c) {
                const int q = c * 4 + kg;
#pragma unroll
                for (int db = 0; db < 6; ++db)
                    bfrag[c][db] = *reinterpret_cast<const bf16x8*>(
                        wk + q * 768 + (db * 16 + r16) * 8);
            }
            if (k + 1 < k1) {
#pragma unroll
                for (int rt = 0; rt < RT; ++rt) {
                    const ushort* as = xbf + ia[rt] * 96 + kg * 8;
#pragma unroll
                    for (int c = 0; c < 3; ++c)
                        aP[rt][c] = *reinterpret_cast<const bf16x8*>(as + c * 32);
                }
            }
            if (k + 2 < k1) {
#pragma unroll
                for (int rt = 0; rt < RT; ++rt)
                    ib[rt] = nbrT[(k + 2) * NPTS + row0 + rt * 16 + r16];
            }
#pragma unroll
            for (int c = 0; c < 3; ++c)
#pragma unroll
                for (int rt = 0; rt < RT; ++rt)
#pragma unroll
                    for (int db = 0; db < 6; ++db)
                        acc[rt][db] = __builtin_amdgcn_mfma_f32_16x16x32_bf16(
                            aQ[rt][c], bfrag[c][db], acc[rt][db], 0, 0, 0);
        }
        ++k; if (k >= k1) break;
    }

    // epilogue: plain contiguous bf16 stores, col-major P[slice][col][n]
    ushort* Ps = P + slice * PSTRIDE;
#pragma unroll
    for (int rt = 0; rt < RT; ++rt) {
        int rowb = row0 + rt * 16 + kg * 4;
#pragma unroll
        for (int db = 0; db < 6; ++db) {
            int col = db * 16 + r16;
            ushort4 o;
            o.x = f2bf(acc[rt][db][0]); o.y = f2bf(acc[rt][db][1]);
            o.z = f2bf(acc[rt][db][2]); o.w = f2bf(acc[rt][db][3]);
            *reinterpret_cast<ushort4*>(Ps + col * NPTS + rowb) = o;
        }
    }
}

// ---------------- stats: sum 4 partial slices -> y (bf16 col-major) + BN stats ----
template <bool SEG>
__global__ __launch_bounds__(256) void k_stats2(const ushort* __restrict__ P,
                                                ushort* __restrict__ y,
                                                float* __restrict__ ssum,
                                                float* __restrict__ ssq,
                                                float* __restrict__ segsum,
                                                const int* __restrict__ boundsI) {
    __shared__ int lb[9];
    __shared__ float red[10][4];
    const int col = blockIdx.x / 12;
    const int chunk = blockIdx.x % 12;
    const int tid = threadIdx.x;
    if (tid < 9) lb[tid] = boundsI[tid];
    __syncthreads();
    const int nbase = chunk * 2500;
    const int cb = col * NPTS;

    float s = 0.f, sq = 0.f;
    float seg[8] = {0.f, 0.f, 0.f, 0.f, 0.f, 0.f, 0.f, 0.f};
    for (int r = tid * 4; r < 2500; r += 1024) {
        int n = nbase + r;
        float v0 = 0.f, v1 = 0.f, v2 = 0.f, v3 = 0.f;
#pragma unroll
        for (int sl = 0; sl < KSPLIT; ++sl) {
            ushort4 u = *reinterpret_cast<const ushort4*>(P + sl * PSTRIDE + cb + n);
            v0 += bf2f(u.x); v1 += bf2f(u.y); v2 += bf2f(u.z); v3 += bf2f(u.w);
        }
        ushort4 o; o.x = f2bf(v0); o.y = f2bf(v1); o.z = f2bf(v2); o.w = f2bf(v3);
        *reinterpret_cast<ushort4*>(y + cb + n) = o;
        s += v0 + v1 + v2 + v3;
        sq += v0 * v0 + v1 * v1 + v2 * v2 + v3 * v3;
        if (SEG) {
            float vv[4] = {v0, v1, v2, v3};
#pragma unroll
            for (int j = 0; j < 4; ++j) {
                int nj = n + j, bb = 0;
#pragma unroll
                for (int t = 1; t < 8; ++t) bb += (nj >= lb[t]) ? 1 : 0;
#pragma unroll
                for (int q = 0; q < 8; ++q) seg[q] += (bb == q) ? vv[j] : 0.f;
            }
        }
    }
    // wave reduce
#pragma unroll
    for (int off = 32; off; off >>= 1) {
        s += __shfl_xor(s, off); sq += __shfl_xor(sq, off);
        if (SEG)
#pragma unroll
            for (int q = 0; q < 8; ++q) seg[q] += __shfl_xor(seg[q], off);
    }
    int wave = tid >> 6, lane = tid & 63;
    if (lane == 0) {
        red[0][wave] = s; red[1][wave] = sq;
        if (SEG)
#pragma unroll
            for (int q = 0; q < 8; ++q) red[2 + q][wave] = seg[q];
    }
    __syncthreads();
    int nred = SEG ? 10 : 2;
    if (tid < nred) {
        float v = red[tid][0] + red[tid][1] + red[tid][2] + red[tid][3];
        if (tid == 0) atomicAdd(&ssum[col], v);
        else if (tid == 1) atomicAdd(&ssq[col], v);
        else atomicAdd(&segsum[(tid - 2) * 96 + col], v);
    }
}

// ---------------- apply1: bn1+relu, col-major y -> row-major h1 bf16 ----------------
__global__ __launch_bounds__(256) void k_apply1(const ushort* __restrict__ y,
                                                const float* __restrict__ ssum,
                                                const float* __restrict__ ssq,
                                                const float* __restrict__ g,
                                                const float* __restrict__ b,
                                                ushort* __restrict__ h1) {
    __shared__ float scale[96], shift[96];
    __shared__ ushort ybuf[96][72];
    bn_coeffs(ssum, ssq, g, b, scale, shift);
    int tid = threadIdx.x;
    int n0 = blockIdx.x * 64;
    int rows = min(64, NPTS - n0);
    for (int it = tid; it < 96 * 16; it += 256) {
        int col = it >> 4, rc = it & 15;
        if (rc * 4 < rows) {
            ushort4 u = *reinterpret_cast<const ushort4*>(y + col * NPTS + n0 + rc * 4);
            float sc = scale[col], sh = shift[col];
            ushort4 o;
            o.x = f2bf(fmaxf(bf2f(u.x) * sc + sh, 0.f));
            o.y = f2bf(fmaxf(bf2f(u.y) * sc + sh, 0.f));
            o.z = f2bf(fmaxf(bf2f(u.z) * sc + sh, 0.f));
            o.w = f2bf(fmaxf(bf2f(u.w) * sc + sh, 0.f));
            *reinterpret_cast<ushort4*>(&ybuf[col][rc * 4]) = o;
        }
    }
    __syncthreads();
    int row = tid >> 2, cg = tid & 3;
    if (row < rows) {
        unsigned int w[12];
#pragma unroll
        for (int j = 0; j < 12; ++j) {
            int c0 = cg * 24 + j * 2;
            unsigned int lo = ybuf[c0][row], hi = ybuf[c0 + 1][row];
            w[j] = lo | (hi << 16);
        }
        uint4* dst = reinterpret_cast<uint4*>(h1 + (n0 + row) * 96 + cg * 24);
        dst[0] = make_uint4(w[0], w[1], w[2], w[3]);
        dst[1] = make_uint4(w[4], w[5], w[6], w[7]);
        dst[2] = make_uint4(w[8], w[9], w[10], w[11]);
    }
}

// SE MLP from raw segment sums: pooled = seg/cnt * scale2 + shift2
__global__ void k_se(const float* __restrict__ segsum, const int* __restrict__ boundsI,
                     const float* __restrict__ ssum, const float* __restrict__ ssq,
                     const float* __restrict__ g, const float* __restrict__ b,
                     const float* __restrict__ fc1w, const float* __restrict__ fc1b,
                     const float* __restrict__ fc2w, const float* __restrict__ fc2b,
                     float* __restrict__ sew) {
    __shared__ float scale[96], shift[96];
    __shared__ float pooled[NB][96];
    __shared__ float hid[NB][HID];
    bn_coeffs(ssum, ssq, g, b, scale, shift);
    int t = threadIdx.x;
    for (int i = t; i < NB * 96; i += 256) {
        int bb = i / 96, d = i - bb * 96;
        float cb = (float)(boundsI[bb + 1] - boundsI[bb]);
        pooled[bb][d] = segsum[i] / fmaxf(cb, 1.f) * scale[d] + shift[d];
    }
    __syncthreads();
    if (t < NB * HID) {
        int bb = t / HID, h = t - bb * HID;
        float s = fc1b[h];
        for (int d = 0; d < 96; ++d) s += pooled[bb][d] * fc1w[d * HID + h];
        hid[bb][h] = fmaxf(s, 0.f);
    }
    __syncthreads();
    for (int i = t; i < NB * 96; i += 256) {
        int bb = i / 96, d = i - bb * 96;
        float s = fc2b[d];
        for (int h = 0; h < HID; ++h) s += hid[bb][h] * fc2w[h * 96 + d];
        sew[i] = 1.f / (1.f + expf(-s));
    }
}

// ---------------- final: relu( bn2(y2)*sew[b] + feats ), col->row transpose ----
__global__ __launch_bounds__(256) void k_final(const ushort* __restrict__ y2,
                                               const float* __restrict__ feats,
                                               const float* __restrict__ ssum,
                                               const float* __restrict__ ssq,
                                               const float* __restrict__ g,
                                               const float* __restrict__ b,
                                               const float* __restrict__ sew,
                                               const int* __restrict__ boundsI,
                                               float* __restrict__ out) {
    __shared__ float scale[96], shift[96];
    __shared__ float fbuf[96][68];
    __shared__ float sewl[NB * 96];
    __shared__ int lb[9];
    bn_coeffs(ssum, ssq, g, b, scale, shift);
    int tid = threadIdx.x;
    for (int i = tid; i < NB * 96; i += 256) sewl[i] = sew[i];
    if (tid < 9) lb[tid] = boundsI[tid];
    int n0 = blockIdx.x * 64;
    int rows = min(64, NPTS - n0);
    for (int it = tid; it < 96 * 16; it += 256) {
        int col = it >> 4, rc = it & 15;
        if (rc * 4 < rows) {
            ushort4 u = *reinterpret_cast<const ushort4*>(y2 + col * NPTS + n0 + rc * 4);
            float sc = scale[col], sh = shift[col];
            f32x4 v;
            v[0] = bf2f(u.x) * sc + sh; v[1] = bf2f(u.y) * sc + sh;
            v[2] = bf2f(u.z) * sc + sh; v[3] = bf2f(u.w) * sc + sh;
            *reinterpret_cast<f32x4*>(&fbuf[col][rc * 4]) = v;
        }
    }
    __syncthreads();
    int row = tid >> 2, cg = tid & 3;
    if (row < rows) {
        int n = n0 + row;
        int bb = 0;
#pragma unroll
        for (int t = 1; t < 8; ++t) bb += (n >= lb[t]) ? 1 : 0;
        const float* swr = &sewl[bb * 96];
        const float* fr = feats + n * 96 + cg * 24;
        float* orow = out + n * 96 + cg * 24;
#pragma unroll
        for (int t4 = 0; t4 < 6; ++t4) {
            float4 fv = *reinterpret_cast<const float4*>(fr + t4 * 4);
            int c0 = cg * 24 + t4 * 4;
            float4 o;
            o.x = fmaxf(fbuf[c0 + 0][row] * swr[c0 + 0] + fv.x, 0.f);
            o.y = fmaxf(fbuf[c0 + 1][row] * swr[c0 + 1] + fv.y, 0.f);
            o.z = fmaxf(fbuf[c0 + 2][row] * swr[c0 + 2] + fv.z, 0.f);
            o.w = fmaxf(fbuf[c0 + 3][row] * swr[c0 + 3] + fv.w, 0.f);
            *reinterpret_cast<float4*>(orow + t4 * 4) = o;
        }
    }
}

// ---------------- launch ----------------

extern "C" void kernel_launch(void* const* d_in, const int* in_sizes, int n_in,
                              void* d_out, int out_size, void* d_ws, size_t ws_size,
                              hipStream_t stream) {
    const float* feats = (const float*)d_in[0];
    const float* W1 = (const float*)d_in[1];
    const float* g1 = (const float*)d_in[2];
    const float* b1 = (const float*)d_in[3];
    const float* W2 = (const float*)d_in[4];
    const float* g2 = (const float*)d_in[5];
    const float* b2 = (const float*)d_in[6];
    const float* fc1w = (const float*)d_in[7];
    const float* fc1b = (const float*)d_in[8];
    const float* fc2w = (const float*)d_in[9];
    const float* fc2b = (const float*)d_in[10];
    const int* nbr = (const int*)d_in[11];
    const int* bids = (const int*)d_in[12];
    float* out = (float*)d_out;

    char* ws = (char*)d_ws;
    ushort* featsbf = (ushort*)(ws + 0);               //  5,760,000 B
    ushort* wt1 = (ushort*)(ws + 5760000);             //  1,492,992 B
    ushort* wt2 = (ushort*)(ws + 7252992);             //  1,492,992 B
    int* nbrT = (int*)(ws + 8745984);                  //  9,720,000 B
    ushort* P = (ushort*)(ws + 18465984);              // 23,040,000 B (4 slices, bf16 col-major)
    ushort* y = (ushort*)(ws + 41505984);              //  5,760,000 B (bf16 col-major)
    ushort* h1bf = (ushort*)(ws + 47265984);           //  5,760,000 B (row-major)
    float* small = (float*)(ws + 53025984);            //     16,384 B
    float* sum1 = small + 0;
    float* sq1 = small + 96;
    float* sum2 = small + 192;
    float* sq2 = small + 288;
    float* segsum = small + 384;   // [8][96]
    float* sew = small + 1152;     // [8][96]
    int* boundsI = (int*)(small + 1920);  // [9]

    const int gC = KSPLIT * GSPLIT;    // 2500 single-wave blocks
    const int gS = 96 * 12;            // stats grid
    const int gT = 469;                // row-tile grid (transpose kernels)

    hipMemsetAsync(small, 0, 16384, stream);
    k_prep<<<3445, 256, 0, stream>>>(feats, W1, W2, nbr, bids, featsbf, nbrT, wt1, wt2, boundsI);

    k_conv<<<gC, 64, 0, stream>>>(featsbf, wt1, nbrT, P);
    k_stats2<false><<<gS, 256, 0, stream>>>(P, y, sum1, sq1, segsum, boundsI);
    k_apply1<<<gT, 256, 0, stream>>>(y, sum1, sq1, g1, b1, h1bf);

    k_conv<<<gC, 64, 0, stream>>>(h1bf, wt2, nbrT, P);
    k_stats2<true><<<gS, 256, 0, stream>>>(P, y, sum2, sq2, segsum, boundsI);

    k_se<<<1, 256, 0, stream>>>(segsum, boundsI, sum2, sq2, g2, b2, fc1w, fc1b, fc2w, fc2b, sew);
    k_final<<<gT, 256, 0, stream>>>(y, feats, sum2, sq2, g2, b2, sew, boundsI, out);
}